// Round 9
// baseline (222.312 us; speedup 1.0000x reference)
//
#include <hip/hip_runtime.h>

#define TT    512
#define WW    257
#define HWSZ  (WW*WW)          // 66049
#define IMG2  (2*HWSZ)         // time stride in `output` (2 channels)
#define SCALE 3.5682482323055424f   // DT^-0.5 / gamma(1.5)
#define KD    163.84f               // KAPPA / DX^2

typedef short bf16x8 __attribute__((ext_vector_type(8)));
typedef short bf16x4 __attribute__((ext_vector_type(4)));
typedef float f32x4  __attribute__((ext_vector_type(4)));
typedef unsigned int u32x4 __attribute__((ext_vector_type(4)));

__device__ __forceinline__ float wf(int j) {
    return sqrtf((float)(j + 1)) - sqrtf((float)j);
}
__device__ __forceinline__ float mcoef(int i, int k) {
    if (i == 0 || k > i) return 0.f;
    if (k == i) return 1.f;
    if (k == 0) return -wf(i - 1);
    int d = i - k;
    return wf(d) - wf(d - 1);
}
__device__ __forceinline__ unsigned short f2b(float f) {
    unsigned u = __float_as_uint(f);
    return (unsigned short)((u + 0x7FFFu + ((u >> 16) & 1u)) >> 16);
}
__device__ __forceinline__ float b2f(unsigned short h) {
    return __uint_as_float(((unsigned)h) << 16);
}

// ---- kernel 1: M as bf16 [512][512] (L2-resident)
__global__ __launch_bounds__(256)
void build_m(unsigned short* __restrict__ M) {
    int i = blockIdx.x;
    for (int k = threadIdx.x; k < TT; k += 256)
        M[i * TT + k] = f2b(mcoef(i, k));
}

// ---- fused: single-PF prefetch staging -> MFMA -> epilogue, 2 blocks/CU.
// grid 1020 = 255 y x 4 x-tiles of 64 px. 512 threads = 8 waves.
// Wave w owns i-tiles [32w,32w+32) and [480-32w,512-32w): 17 k-subs (balanced).
__global__ __launch_bounds__(512, 4)
void fused(const float* __restrict__ uin, const float* __restrict__ f1p,
           const float* __restrict__ lapk, const unsigned short* __restrict__ Mb,
           float* __restrict__ d_out)
{
    __shared__ unsigned short uS[2][64][64];   // [buf][px][t-local], XOR-swizzled segs
    __shared__ unsigned short sS[2][64][68];   // [buf][t-local][px]
    __shared__ float red[8];

    const int tid  = threadIdx.x;
    const int w    = tid >> 6;
    const int lane = tid & 63;
    const int lr   = lane & 15;
    const int lg   = lane >> 4;

    // bijective XCD chunking over 1020 blocks; consecutive wg = consecutive y
    const int bid = blockIdx.x;
    const int xcd = bid & 7, idx = bid >> 3;
    const int wg  = (xcd < 4 ? xcd * 128 : 512 + (xcd - 4) * 127) + idx;
    const int y   = 1 + wg % 255;
    const int c0  = (wg / 255) * 64;        // px-column base (image x = px+1)

    const float ka = lapk[0];   // corner
    const float kb = lapk[1];   // edge
    const float kc = lapk[4];   // center

    f32x4 acc0[4][2], acc1[4][2];
    #pragma unroll
    for (int a = 0; a < 4; ++a) {
        acc0[a][0] = (f32x4)0.f; acc0[a][1] = (f32x4)0.f;
        acc1[a][0] = (f32x4)0.f; acc1[a][1] = (f32x4)0.f;
    }

    const bool pad = (c0 + lane) == 255;      // last px column is the zero pad
    const int  i00 = 32 * w;
    const int  i01 = 480 - 32 * w;
    const int  ec0 = w >> 1;                  // chunk where half0 completes
    const int  ec1 = (15 - w) >> 1;           // chunk where half1 completes
    float lsum = 0.f;

    // single register prefetch buffer (issue->use distance unchanged: WAR only)
    float a0[8], a1[8], a2[8], fv[8], ee;

    // edge-gather lane mapping: l<24 -> left col c0, 24<=l<48 -> right col c0+65;
    // rr = triple index (t-row), ej = y-offset 0..2
    const int  gl   = (lane < 48) ? lane : 47;
    const int  gside= gl >= 24;
    const int  gidx = gside ? gl - 24 : gl;
    const int  grr  = gidx / 3;
    const int  gej  = gidx - 3 * grr;
    const size_t geoff = (size_t)grr * IMG2 + (size_t)(y - 1 + gej) * WW
                       + (gside ? c0 + 65 : c0);
    const int  li3  = lane - (lane % 3);      // triple base for Qe combine

    auto LOADR = [&](int c) {
        const int tb = 64 * c + 8 * w;
        const float* pu = uin + (size_t)tb * IMG2 + (size_t)(y - 1) * WW + (c0 + 1) + lane;
        const float* pf = f1p + (size_t)tb * HWSZ + (size_t)y * WW + (c0 + 1) + lane;
        #pragma unroll
        for (int rr = 0; rr < 8; ++rr) {
            const float* qu = pu + (size_t)rr * IMG2;
            a0[rr] = qu[0]; a1[rr] = qu[WW]; a2[rr] = qu[2 * WW];
            fv[rr] = pf[(size_t)rr * HWSZ];
        }
        ee = uin[(size_t)tb * IMG2 + geoff];   // 48-lane edge gather, 1 reg
    };

    auto STAGE = [&](int b) {
        // edge Q values, computed once per chunk (valid at lanes < 48)
        float v0 = __shfl(ee, li3, 64);
        float v1 = __shfl(ee, li3 + 1, 64);
        float v2 = __shfl(ee, li3 + 2, 64);
        float Qe = fmaf(ka, v0 + v2, kb * v1);
        u32x4 up;
        #pragma unroll
        for (int rr = 0; rr < 8; ++rr) {
            float P  = a0[rr] + a2[rr];
            float Q  = fmaf(ka, P, kb * a1[rr]);
            float Rr = fmaf(kb, P, kc * a1[rr]);
            float qm = __shfl(Q, lane - 1, 64);
            float qp = __shfl(Q, lane + 1, 64);
            float ql = __shfl(Qe, 3 * rr, 64);        // left edge of row rr
            float qr = __shfl(Qe, 24 + 3 * rr, 64);   // right edge of row rr
            if (lane == 0)  qm = ql;
            if (lane == 63) qp = qr;
            float lap = qm + qp + Rr;
            float s   = a1[rr] - fmaf(KD, lap, fv[rr]);
            unsigned short sb = pad ? (unsigned short)0 : f2b(s);
            unsigned short ub = pad ? (unsigned short)0 : f2b(a1[rr]);
            sS[b][8 * w + rr][lane] = sb;
            if (rr & 1) up[rr >> 1] |= ((unsigned)ub) << 16;
            else        up[rr >> 1]  = (unsigned)ub;
        }
        *(u32x4*)&uS[b][lane][(w ^ (lane & 7)) * 8] = up;   // conflict-free b128
    };

    auto EPI = [&](f32x4 (&acc)[4][2], int b, int lbase) {
        #pragma unroll
        for (int mi = 0; mi < 4; ++mi)
            #pragma unroll
            for (int nj = 0; nj < 2; ++nj) {
                bf16x4 sv = *(const bf16x4*)&sS[b][lbase + 16 * nj + lr][16 * mi + 4 * lg];
                #pragma unroll
                for (int r = 0; r < 4; ++r) {
                    float res = SCALE * acc[mi][nj][r] + b2f((unsigned short)sv[r]);
                    lsum += res * res;
                }
            }
    };

    LOADR(0);
    for (int c = 0; c < 8; ++c) {
        const int b = c & 1;

        STAGE(b);                      // waits on chunk-c loads, writes LDS buf b
        if (c < 7) LOADR(c + 1);       // reissue into same regs (WAR), drains in bg
        __syncthreads();               // single barrier per chunk (double-buffered LDS)

        #pragma unroll
        for (int sub = 0; sub < 2; ++sub) {
            const int s_ = 2 * c + sub;
            if (s_ <= w) {                               // half0
                const unsigned short* mb = Mb + (size_t)(i00 + lr) * TT + 64 * c + 32 * sub + 8 * lg;
                bf16x8 b0 = *(const bf16x8*)mb;
                bf16x8 b1 = *(const bf16x8*)(mb + 16 * TT);
                #pragma unroll
                for (int mi = 0; mi < 4; ++mi) {
                    bf16x8 a = *(const bf16x8*)&uS[b][16 * mi + lr][((4 * sub + lg) ^ (lr & 7)) * 8];
                    acc0[mi][0] = __builtin_amdgcn_mfma_f32_16x16x32_bf16(a, b0, acc0[mi][0], 0, 0, 0);
                    acc0[mi][1] = __builtin_amdgcn_mfma_f32_16x16x32_bf16(a, b1, acc0[mi][1], 0, 0, 0);
                }
            }
            if (s_ <= 15 - w) {                          // half1
                const unsigned short* mb = Mb + (size_t)(i01 + lr) * TT + 64 * c + 32 * sub + 8 * lg;
                bf16x8 b0 = *(const bf16x8*)mb;
                bf16x8 b1 = *(const bf16x8*)(mb + 16 * TT);
                #pragma unroll
                for (int mi = 0; mi < 4; ++mi) {
                    bf16x8 a = *(const bf16x8*)&uS[b][16 * mi + lr][((4 * sub + lg) ^ (lr & 7)) * 8];
                    acc1[mi][0] = __builtin_amdgcn_mfma_f32_16x16x32_bf16(a, b0, acc1[mi][0], 0, 0, 0);
                    acc1[mi][1] = __builtin_amdgcn_mfma_f32_16x16x32_bf16(a, b1, acc1[mi][1], 0, 0, 0);
                }
            }
        }

        if (c == ec0) EPI(acc0, b, (w & 1) * 32);
        if (c == ec1) EPI(acc1, b, ((w + 1) & 1) * 32);
    }

    // ---------- reduce: wave shfl -> LDS -> one atomic per block ----------
    #pragma unroll
    for (int off = 32; off > 0; off >>= 1)
        lsum += __shfl_down(lsum, off, 64);
    if (lane == 0) red[w] = lsum;
    __syncthreads();
    if (tid == 0) {
        float tot = 0.f;
        #pragma unroll
        for (int q = 0; q < 8; ++q) tot += red[q];
        atomicAdd(d_out, tot * (1.0f / 33292800.0f));
    }
}

extern "C" void kernel_launch(void* const* d_in, const int* in_sizes, int n_in,
                              void* d_out, int out_size, void* d_ws, size_t ws_size,
                              hipStream_t stream)
{
    const float* uin  = (const float*)d_in[0];
    const float* f1   = (const float*)d_in[1];
    const float* lapk = (const float*)d_in[2];
    float* out = (float*)d_out;

    unsigned short* Mb = (unsigned short*)d_ws;   // 512 KB

    hipMemsetAsync(out, 0, sizeof(float), stream);
    build_m<<<dim3(TT), 256, 0, stream>>>(Mb);
    fused<<<dim3(1020), 512, 0, stream>>>(uin, f1, lapk, Mb, out);
}

// Round 10
// 129.686 us; speedup vs baseline: 1.7142x; 1.7142x over previous
//
#include <hip/hip_runtime.h>

#define TT    512
#define WW    257
#define HWSZ  (WW*WW)          // 66049
#define IMG2  (2*HWSZ)         // time stride in `output` (2 channels)
#define SCALE 3.5682482323055424f   // DT^-0.5 / gamma(1.5)
#define KD    163.84f               // KAPPA / DX^2

typedef short bf16x8 __attribute__((ext_vector_type(8)));
typedef short bf16x4 __attribute__((ext_vector_type(4)));
typedef float f32x4  __attribute__((ext_vector_type(4)));

__device__ __forceinline__ float wf(int j) {
    return sqrtf((float)(j + 1)) - sqrtf((float)j);
}
__device__ __forceinline__ float mcoef(int i, int k) {
    if (i == 0 || k > i) return 0.f;
    if (k == i) return 1.f;
    if (k == 0) return -wf(i - 1);
    int d = i - k;
    return wf(d) - wf(d - 1);
}
__device__ __forceinline__ unsigned short f2b(float f) {
    unsigned u = __float_as_uint(f);
    return (unsigned short)((u + 0x7FFFu + ((u >> 16) & 1u)) >> 16);
}
__device__ __forceinline__ float b2f(unsigned short h) {
    return __uint_as_float(((unsigned)h) << 16);
}

// async global->LDS, width 4 (per-lane global src, wave-uniform LDS dest + lane*4)
__device__ __forceinline__ void gldsf(const float* g, float* l) {
    __builtin_amdgcn_global_load_lds((const __attribute__((address_space(1))) void*)g,
                                     (__attribute__((address_space(3))) void*)l, 4, 0, 0);
}

// ---- kernel 1: M as bf16 [512][512] (L2-resident)
__global__ __launch_bounds__(256)
void build_m(unsigned short* __restrict__ M) {
    int i = blockIdx.x;
    for (int k = threadIdx.x; k < TT; k += 256)
        M[i * TT + k] = f2b(mcoef(i, k));
}

// ---- fused: async-LDS staging, counted vmcnt, raw barriers, 2 blocks/CU.
// grid 1020 = 255 y x 4 x-tiles of 64 px. 512 thr = 8 waves. chunk = 32 t (16 chunks).
// Wave w owns i-tiles [32w,32w+32) (subs c<=w) and [480-32w,512-32w) (subs c<=15-w): 17 subs each.
__global__ __launch_bounds__(512, 4)
void fused(const float* __restrict__ uin, const float* __restrict__ f1p,
           const float* __restrict__ lapk, const unsigned short* __restrict__ Mb,
           float* __restrict__ d_out)
{
    __shared__ float          uRaw[2][32][3][64];   // 48 KB raw u (own-wave rows)
    __shared__ unsigned short uS[2][64][32];        // 8 KB  A-tile [px][t], 16B-seg swizzled
    __shared__ unsigned short sS[2][32][72];        // 9 KB  s [t][px] (+pad)
    __shared__ float red[8];

    const int tid  = threadIdx.x;
    const int w    = tid >> 6;
    const int lane = tid & 63;
    const int lr   = lane & 15;
    const int lg   = lane >> 4;

    // bijective XCD chunking; consecutive wg = consecutive y (L2 row reuse)
    const int bid = blockIdx.x;
    const int xcd = bid & 7, idx = bid >> 3;
    const int wg  = (xcd < 4 ? xcd * 128 : 512 + (xcd - 4) * 127) + idx;
    const int y   = 1 + wg % 255;
    const int c0  = (wg / 255) * 64;        // px-column base (image x = px+1)

    const float ka = lapk[0];   // corner
    const float kb = lapk[1];   // edge
    const float kc = lapk[4];   // center

    f32x4 acc0[4][2], acc1[4][2];
    #pragma unroll
    for (int a = 0; a < 4; ++a) {
        acc0[a][0] = (f32x4)0.f; acc0[a][1] = (f32x4)0.f;
        acc1[a][0] = (f32x4)0.f; acc1[a][1] = (f32x4)0.f;
    }

    const bool pad = (c0 + lane) == 255;
    const int  i00 = 32 * w;
    const int  i01 = 480 - 32 * w;

    // edge-gather map: lane<24: tlj=l/6, side=(l%6)/3, yr=(l%6)%3
    const int gl  = (lane < 24) ? lane : 23;
    const int tlj = gl / 6, rem = gl - 6 * tlj;
    const int side = rem / 3, yrj = rem - 3 * side;
    const size_t geoff = (size_t)(4 * w + tlj) * IMG2 + (size_t)(y - 1 + yrj) * WW
                       + (side ? c0 + 65 : c0);

    float fv0, fv1, fv2, fv3, ee;
    float lsum = 0.f;

    // ---- prologue: stage chunk 0
    {
        const size_t tb = (size_t)(4 * w) * IMG2 + (size_t)(y - 1) * WW + (c0 + 1) + lane;
        #pragma unroll
        for (int j = 0; j < 4; ++j)
            #pragma unroll
            for (int yr = 0; yr < 3; ++yr)
                gldsf(uin + tb + (size_t)j * IMG2 + (size_t)yr * WW, &uRaw[0][4 * w + j][yr][0]);
        const size_t fb = (size_t)(4 * w) * HWSZ + (size_t)y * WW + (c0 + 1) + lane;
        fv0 = f1p[fb]; fv1 = f1p[fb + HWSZ]; fv2 = f1p[fb + 2 * HWSZ]; fv3 = f1p[fb + 3 * HWSZ];
        ee  = uin[geoff];
    }

    for (int c = 0; c < 16; ++c) {
        const int b = c & 1;

        // A0: preload M fragments (L2 hits; older than next GLDS batch -> non-draining waits)
        bf16x8 mb00, mb01, mb10, mb11;
        if (c <= w) {
            const unsigned short* mp = Mb + (size_t)(i00 + lr) * TT + 32 * c + 8 * lg;
            mb00 = *(const bf16x8*)mp; mb01 = *(const bf16x8*)(mp + 16 * TT);
        }
        if (c <= 15 - w) {
            const unsigned short* mp = Mb + (size_t)(i01 + lr) * TT + 32 * c + 8 * lg;
            mb10 = *(const bf16x8*)mp; mb11 = *(const bf16x8*)(mp + 16 * TT);
        }

        // A1: issue next chunk's 12 async LDS loads, then counted wait for chunk c
        if (c < 15) {
            const size_t tb = (size_t)(32 * (c + 1) + 4 * w) * IMG2
                            + (size_t)(y - 1) * WW + (c0 + 1) + lane;
            #pragma unroll
            for (int j = 0; j < 4; ++j)
                #pragma unroll
                for (int yr = 0; yr < 3; ++yr)
                    gldsf(uin + tb + (size_t)j * IMG2 + (size_t)yr * WW,
                          &uRaw[b ^ 1][4 * w + j][yr][0]);
            asm volatile("s_waitcnt vmcnt(12)" ::: "memory");   // chunk-c data landed; 12 in flight
        } else {
            asm volatile("s_waitcnt vmcnt(0)" ::: "memory");
        }
        __builtin_amdgcn_sched_barrier(0);

        // C: stencil from own uRaw rows -> sS + packed uS centers
        unsigned int upk0, upk1;
        #pragma unroll
        for (int j = 0; j < 4; ++j) {
            float h0 = uRaw[b][4 * w + j][0][lane];
            float h1 = uRaw[b][4 * w + j][1][lane];
            float h2 = uRaw[b][4 * w + j][2][lane];
            float fvj = (j == 0) ? fv0 : (j == 1) ? fv1 : (j == 2) ? fv2 : fv3;
            float P = h0 + h2;
            float Q  = fmaf(ka, P, kb * h1);
            float Rr = fmaf(kb, P, kc * h1);
            float qm = __shfl(Q, lane - 1, 64);
            float qp = __shfl(Q, lane + 1, 64);
            float eL0 = __shfl(ee, 6 * j, 64), eL1 = __shfl(ee, 6 * j + 1, 64), eL2 = __shfl(ee, 6 * j + 2, 64);
            float eR0 = __shfl(ee, 6 * j + 3, 64), eR1 = __shfl(ee, 6 * j + 4, 64), eR2 = __shfl(ee, 6 * j + 5, 64);
            if (lane == 0)  qm = fmaf(ka, eL0 + eL2, kb * eL1);
            if (lane == 63) qp = fmaf(ka, eR0 + eR2, kb * eR1);
            float lap = qm + qp + Rr;
            float s   = h1 - fmaf(KD, lap, fvj);
            unsigned short sb = pad ? (unsigned short)0 : f2b(s);
            unsigned short ub = pad ? (unsigned short)0 : f2b(h1);
            sS[b][4 * w + j][lane] = sb;
            if (j == 0) upk0 = (unsigned)ub;
            if (j == 1) upk0 |= ((unsigned)ub) << 16;
            if (j == 2) upk1 = (unsigned)ub;
            if (j == 3) upk1 |= ((unsigned)ub) << 16;
        }
        {   // one 8B swizzled write: row=lane(px), seg=(w>>1)^((lane>>1)&3), half=w&1
            uint2 uv; uv.x = upk0; uv.y = upk1;
            *(uint2*)((char*)&uS[b][lane][0]
                      + (((w >> 1) ^ ((lane >> 1) & 3)) * 16 + (w & 1) * 8)) = uv;
        }

        // D: reg loads for next chunk (f1 + edges) — issued after consumption (WAR-safe)
        if (c < 15) {
            const size_t fb = (size_t)(32 * (c + 1) + 4 * w) * HWSZ
                            + (size_t)y * WW + (c0 + 1) + lane;
            fv0 = f1p[fb]; fv1 = f1p[fb + HWSZ]; fv2 = f1p[fb + 2 * HWSZ]; fv3 = f1p[fb + 3 * HWSZ];
            ee  = uin[(size_t)(32 * (c + 1)) * IMG2 + geoff];
        }

        // E: publish uS/sS (LDS only) — raw barrier, NO vmcnt drain
        asm volatile("s_waitcnt lgkmcnt(0)" ::: "memory");
        __builtin_amdgcn_sched_barrier(0);
        __builtin_amdgcn_s_barrier();
        __builtin_amdgcn_sched_barrier(0);

        // F: MFMA (k-sub c), A-frags from swizzled uS
        if (c <= w) {
            #pragma unroll
            for (int mi = 0; mi < 4; ++mi) {
                bf16x8 a = *(const bf16x8*)((char*)&uS[b][16 * mi + lr][0]
                                            + ((lg ^ ((lr >> 1) & 3)) * 16));
                acc0[mi][0] = __builtin_amdgcn_mfma_f32_16x16x32_bf16(a, mb00, acc0[mi][0], 0, 0, 0);
                acc0[mi][1] = __builtin_amdgcn_mfma_f32_16x16x32_bf16(a, mb01, acc0[mi][1], 0, 0, 0);
            }
        }
        if (c <= 15 - w) {
            #pragma unroll
            for (int mi = 0; mi < 4; ++mi) {
                bf16x8 a = *(const bf16x8*)((char*)&uS[b][16 * mi + lr][0]
                                            + ((lg ^ ((lr >> 1) & 3)) * 16));
                acc1[mi][0] = __builtin_amdgcn_mfma_f32_16x16x32_bf16(a, mb10, acc1[mi][0], 0, 0, 0);
                acc1[mi][1] = __builtin_amdgcn_mfma_f32_16x16x32_bf16(a, mb11, acc1[mi][1], 0, 0, 0);
            }
        }

        // G: epilogues due this chunk (sS[b] is this chunk's t-range)
        if (c == w) {
            #pragma unroll
            for (int mi = 0; mi < 4; ++mi)
                #pragma unroll
                for (int nj = 0; nj < 2; ++nj) {
                    bf16x4 sv = *(const bf16x4*)&sS[b][16 * nj + lr][16 * mi + 4 * lg];
                    #pragma unroll
                    for (int r = 0; r < 4; ++r) {
                        float res = SCALE * acc0[mi][nj][r] + b2f((unsigned short)sv[r]);
                        lsum += res * res;
                    }
                }
        }
        if (c == 15 - w) {
            #pragma unroll
            for (int mi = 0; mi < 4; ++mi)
                #pragma unroll
                for (int nj = 0; nj < 2; ++nj) {
                    bf16x4 sv = *(const bf16x4*)&sS[b][16 * nj + lr][16 * mi + 4 * lg];
                    #pragma unroll
                    for (int r = 0; r < 4; ++r) {
                        float res = SCALE * acc1[mi][nj][r] + b2f((unsigned short)sv[r]);
                        lsum += res * res;
                    }
                }
        }
    }

    // ---- reduce: wave shfl -> LDS -> one atomic per block
    #pragma unroll
    for (int off = 32; off > 0; off >>= 1)
        lsum += __shfl_down(lsum, off, 64);
    if (lane == 0) red[w] = lsum;
    __syncthreads();
    if (tid == 0) {
        float tot = 0.f;
        #pragma unroll
        for (int q = 0; q < 8; ++q) tot += red[q];
        atomicAdd(d_out, tot * (1.0f / 33292800.0f));
    }
}

extern "C" void kernel_launch(void* const* d_in, const int* in_sizes, int n_in,
                              void* d_out, int out_size, void* d_ws, size_t ws_size,
                              hipStream_t stream)
{
    const float* uin  = (const float*)d_in[0];
    const float* f1   = (const float*)d_in[1];
    const float* lapk = (const float*)d_in[2];
    float* out = (float*)d_out;

    unsigned short* Mb = (unsigned short*)d_ws;   // 512 KB

    hipMemsetAsync(out, 0, sizeof(float), stream);
    build_m<<<dim3(TT), 256, 0, stream>>>(Mb);
    fused<<<dim3(1020), 512, 0, stream>>>(uin, f1, lapk, Mb, out);
}